// Round 9
// baseline (583.662 us; speedup 1.0000x reference)
//
#include <hip/hip_runtime.h>
#include <math.h>

// ---------------------------------------------------------------------------
// GCN 2-layer forward on MI355X. Round 9: reorder layer 1 using
// A(X W1) = (A X) W1 and fuse BOTH GEMMs into the gather kernel.
//   castxw: xb = bf16(x), W1t/W2t transposed bf16 casts (one kernel)
//   megafused (per block = 16 nodes):
//     phase A: gather (A xb) rows -> LDS r0[16][264]          (fp32 accum)
//     phase B: r1 = bf16(relu(r0 @ W1 + b1))  [32 MFMA/wave] -> LDS
//     phase C: h2b = bf16(r1 @ W2)            [ 8 MFMA/wave]
//   agg64: out = log_softmax(A h2b + b2)  (unchanged)
//   gemm1/aggfused dispatches are gone; h1b buffer is gone.
// ---------------------------------------------------------------------------

typedef __attribute__((ext_vector_type(8))) short bf16x8;
typedef __attribute__((ext_vector_type(4))) float f32x4;

__device__ inline unsigned short f2bf(float f) {
    union { float f; unsigned int u; } v; v.f = f;
    unsigned int r = v.u + 0x7fffu + ((v.u >> 16) & 1u);  // RNE
    return (unsigned short)(r >> 16);
}
__device__ inline float bf2f_lo(unsigned int u) {
    union { unsigned int u; float f; } v; v.u = u << 16; return v.f;
}
__device__ inline float bf2f_hi(unsigned int u) {
    union { unsigned int u; float f; } v; v.u = u & 0xffff0000u; return v.f;
}

// unpack uint4 (8 bf16) and FMA into acc[8] with weight w
__device__ inline void acc8(float* acc, uint4 q, float w) {
    acc[0] += bf2f_lo(q.x) * w; acc[1] += bf2f_hi(q.x) * w;
    acc[2] += bf2f_lo(q.y) * w; acc[3] += bf2f_hi(q.y) * w;
    acc[4] += bf2f_lo(q.z) * w; acc[5] += bf2f_hi(q.z) * w;
    acc[6] += bf2f_lo(q.w) * w; acc[7] += bf2f_hi(q.w) * w;
}

// ---------------- CSR build ----------------
__global__ __launch_bounds__(256) void deg_rank_kernel(
    const int* __restrict__ dst, int E, int* __restrict__ cnt,
    int* __restrict__ rank) {
    int e = blockIdx.x * blockDim.x + threadIdx.x;
    if (e < E) rank[e] = atomicAdd(&cnt[dst[e]], 1);
}

__global__ __launch_bounds__(256) void scan_part1_kernel(
    const int* __restrict__ cnt, int* __restrict__ bsum, int N) {
    __shared__ int s[256];
    const int tid = threadIdx.x;
    int base = blockIdx.x * 1024 + tid * 4;
    int v = 0;
#pragma unroll
    for (int j = 0; j < 4; ++j)
        if (base + j < N) v += cnt[base + j];
    s[tid] = v;
    __syncthreads();
    for (int off = 128; off > 0; off >>= 1) {
        if (tid < off) s[tid] += s[tid + off];
        __syncthreads();
    }
    if (tid == 0) bsum[blockIdx.x] = s[0];
}

__global__ __launch_bounds__(1024) void scan_part2_kernel(
    const int* __restrict__ bsum, int* __restrict__ boffs, int NB,
    int* __restrict__ row_ptr, int N) {
    __shared__ int s[1024];
    const int tid = threadIdx.x;
    int v = (tid < NB) ? bsum[tid] : 0;
    s[tid] = v;
    __syncthreads();
    for (int off = 1; off < 1024; off <<= 1) {
        int t = (tid >= off) ? s[tid - off] : 0;
        __syncthreads();
        if (tid >= off) s[tid] += t;
        __syncthreads();
    }
    if (tid < NB) boffs[tid] = s[tid] - v;  // exclusive
    if (tid == 1023) row_ptr[N] = s[1023];  // grand total
}

__global__ __launch_bounds__(256) void scan_part3_kernel(
    const int* __restrict__ cnt, const int* __restrict__ boffs,
    int* __restrict__ row_ptr, int N) {
    __shared__ int s[256];
    const int tid = threadIdx.x;
    int base = blockIdx.x * 1024 + tid * 4;
    int c[4];
    int v = 0;
#pragma unroll
    for (int j = 0; j < 4; ++j) {
        c[j] = (base + j < N) ? cnt[base + j] : 0;
        v += c[j];
    }
    s[tid] = v;
    __syncthreads();
    for (int off = 1; off < 256; off <<= 1) {
        int t = (tid >= off) ? s[tid - off] : 0;
        __syncthreads();
        if (tid >= off) s[tid] += t;
        __syncthreads();
    }
    int run = boffs[blockIdx.x] + s[tid] - v;
#pragma unroll
    for (int j = 0; j < 4; ++j) {
        if (base + j < N) {
            row_ptr[base + j] = run;
            run += c[j];
        }
    }
}

// Atomic-free scatter: slot = row_ptr[dst] + rank.
__global__ __launch_bounds__(256) void scatter_kernel(
    const int* __restrict__ src, const int* __restrict__ dst,
    const int* __restrict__ rank, const int* __restrict__ cnt,
    const int* __restrict__ row_ptr, int2* __restrict__ csr_ew, int E) {
    int e = blockIdx.x * blockDim.x + threadIdx.x;
    if (e >= E) return;
    int s = src[e], d = dst[e];
    float w = rsqrtf((float)cnt[s] + 1.0f) * rsqrtf((float)cnt[d] + 1.0f);
    int pos = row_ptr[d] + rank[e];
    int2 rec;
    rec.x = s;
    rec.y = __float_as_int(w);
    csr_ew[pos] = rec;
}

// ---- merged casts: xb = bf16(x) (vectorized); W1t/W2t transposed bf16 ----
__global__ __launch_bounds__(256) void castxw_kernel(
    const float* __restrict__ x, const float* __restrict__ W1,
    const float* __restrict__ W2, unsigned int* __restrict__ xb,
    unsigned short* __restrict__ W1t, unsigned short* __restrict__ W2t,
    int NX8) {  // NX8 = N*256/8
    int i = blockIdx.x * 256 + threadIdx.x;
    if (i < NX8) {
        const float4* xp = (const float4*)&x[(size_t)i * 8];
        float4 a0 = xp[0], a1 = xp[1];
        uint4 o;
        o.x = (unsigned int)f2bf(a0.x) | ((unsigned int)f2bf(a0.y) << 16);
        o.y = (unsigned int)f2bf(a0.z) | ((unsigned int)f2bf(a0.w) << 16);
        o.z = (unsigned int)f2bf(a1.x) | ((unsigned int)f2bf(a1.y) << 16);
        o.w = (unsigned int)f2bf(a1.z) | ((unsigned int)f2bf(a1.w) << 16);
        *(uint4*)&xb[(size_t)i * 4] = o;
    } else if (i < NX8 + 65536) {  // W1: 256x256 -> W1t[n][k]
        int j = i - NX8;
        int n = j >> 8, k = j & 255;
        W1t[j] = f2bf(W1[(size_t)k * 256 + n]);
    } else if (i < NX8 + 65536 + 16384) {  // W2: 256x64 -> W2t[64][256]
        int j = i - NX8 - 65536;
        int n = j >> 8, k = j & 255;
        W2t[j] = f2bf(W2[(size_t)k * 64 + n]);
    }
}

// ---- MEGAFUSED: h2b = bf16( relu((A xb) @ W1 + b1) @ W2 ), 16 nodes/blk ---
__global__ __launch_bounds__(256) void megafused_kernel(
    const uint4* __restrict__ h,  // xb rows = 32 uint4 (256 bf16)
    const int2* __restrict__ ew,
    const int* __restrict__ row_ptr, const int* __restrict__ cnt,
    const float* __restrict__ b1, const unsigned short* __restrict__ W1t,
    const unsigned short* __restrict__ W2t,
    unsigned short* __restrict__ h2b, int N) {
    __shared__ unsigned short r0[16][264];  // agg rows (bf16), +8 pad
    __shared__ unsigned short r1[16][264];  // relu(r0 W1 + b1) rows

    const int tid = threadIdx.x;
    const int wave = tid >> 6, lane = tid & 63;
    const int half = lane >> 5;
    const int c = lane & 31;
    const int node0 = blockIdx.x * 16;

    // ---- phase A: gather (A xb) rows into r0 (no bias/relu) ----
    for (int i = 0; i < 4; ++i) {
        const int local = wave * 4 + i;
        const int node = node0 + local;
        float acc[8] = {0.f, 0.f, 0.f, 0.f, 0.f, 0.f, 0.f, 0.f};
        if (node < N) {
            float dv = rsqrtf((float)cnt[node] + 1.0f);
            float w0 = dv * dv;
            {
                uint4 q = h[(size_t)node * 32 + c];
                acc8(acc, q, half == 0 ? w0 : 0.f);
            }
            const int beg = row_ptr[node], end = row_ptr[node + 1];
            int e = beg;
            for (; e + 8 <= end; e += 8) {
                int2 p0 = ew[e + 0 + half];
                int2 p1 = ew[e + 2 + half];
                int2 p2 = ew[e + 4 + half];
                int2 p3 = ew[e + 6 + half];
                uint4 q0 = h[(size_t)p0.x * 32 + c];
                uint4 q1 = h[(size_t)p1.x * 32 + c];
                uint4 q2 = h[(size_t)p2.x * 32 + c];
                uint4 q3 = h[(size_t)p3.x * 32 + c];
                acc8(acc, q0, __int_as_float(p0.y));
                acc8(acc, q1, __int_as_float(p1.y));
                acc8(acc, q2, __int_as_float(p2.y));
                acc8(acc, q3, __int_as_float(p3.y));
            }
            for (; e < end; e += 2) {
                int idx = e + half;
                int idxc = min(idx, end - 1);
                int2 r = ew[idxc];
                float w = (idx < end) ? __int_as_float(r.y) : 0.f;
                uint4 q = h[(size_t)r.x * 32 + c];
                acc8(acc, q, w);
            }
        }
#pragma unroll
        for (int k = 0; k < 8; ++k) acc[k] += __shfl_xor(acc[k], 32, 64);

        if (half == 0) {
            uint4 ov;
            ov.x = (unsigned int)f2bf(acc[0]) | ((unsigned int)f2bf(acc[1]) << 16);
            ov.y = (unsigned int)f2bf(acc[2]) | ((unsigned int)f2bf(acc[3]) << 16);
            ov.z = (unsigned int)f2bf(acc[4]) | ((unsigned int)f2bf(acc[5]) << 16);
            ov.w = (unsigned int)f2bf(acc[6]) | ((unsigned int)f2bf(acc[7]) << 16);
            *(uint4*)&r0[local][c * 8] = ov;
        }
    }
    __syncthreads();

    // ---- phase B: r1 = bf16(relu(r0 @ W1 + b1)). Wave w: cols [64w,64w+64).
    const int quad = lane >> 4, l15 = lane & 15;
    {
        f32x4 accb[4] = {};
#pragma unroll
        for (int k0 = 0; k0 < 8; ++k0) {
            bf16x8 af = *(const bf16x8*)&r0[l15][k0 * 32 + quad * 8];
#pragma unroll
            for (int nt = 0; nt < 4; ++nt) {
                bf16x8 bf = *(const bf16x8*)&W1t[
                    (size_t)(wave * 64 + nt * 16 + l15) * 256 + k0 * 32 + quad * 8];
                accb[nt] = __builtin_amdgcn_mfma_f32_16x16x32_bf16(
                    af, bf, accb[nt], 0, 0, 0);
            }
        }
#pragma unroll
        for (int nt = 0; nt < 4; ++nt) {
            int col = wave * 64 + nt * 16 + l15;
            float bb = b1[col];
#pragma unroll
            for (int r = 0; r < 4; ++r) {
                int row = quad * 4 + r;
                r1[row][col] = f2bf(fmaxf(accb[nt][r] + bb, 0.f));
            }
        }
    }
    __syncthreads();

    // ---- phase C: h2b = bf16(r1 @ W2). Wave w: cols [16w, 16w+16). ----
    f32x4 accd = {};
#pragma unroll
    for (int k0 = 0; k0 < 8; ++k0) {
        bf16x8 af = *(const bf16x8*)&r1[l15][k0 * 32 + quad * 8];
        bf16x8 bf = *(const bf16x8*)&W2t[(size_t)(wave * 16 + l15) * 256 +
                                         k0 * 32 + quad * 8];
        accd = __builtin_amdgcn_mfma_f32_16x16x32_bf16(af, bf, accd, 0, 0, 0);
    }
#pragma unroll
    for (int r = 0; r < 4; ++r) {
        int node = node0 + quad * 4 + r;
        if (node < N)
            h2b[(size_t)node * 64 + wave * 16 + l15] = f2bf(accd[r]);
    }
}

// ---- out = log_softmax(A h2b + b2), F=64 ----------------------------------
__global__ __launch_bounds__(256) void agg64_kernel(
    const uint4* __restrict__ h,  // row = 8 uint4 (64 bf16)
    const int2* __restrict__ ew, const int* __restrict__ row_ptr,
    const int* __restrict__ cnt, const float* __restrict__ bias,
    float* __restrict__ out, int N) {
    const int node = blockIdx.x * 4 + (threadIdx.x >> 6);
    if (node >= N) return;
    const int lane = threadIdx.x & 63;
    const int g = lane >> 3;
    const int c = lane & 7;

    float dv = rsqrtf((float)cnt[node] + 1.0f);
    float w0 = dv * dv;

    float acc[8] = {0.f, 0.f, 0.f, 0.f, 0.f, 0.f, 0.f, 0.f};
    {
        uint4 q = h[(size_t)node * 8 + c];
        acc8(acc, q, g == 0 ? w0 : 0.f);
    }

    const int beg = row_ptr[node], end = row_ptr[node + 1];
    int e = beg;
    for (; e + 16 <= end; e += 16) {
        int2 r0 = ew[e + g];
        int2 r1 = ew[e + 8 + g];
        uint4 q0 = h[(size_t)r0.x * 8 + c];
        uint4 q1 = h[(size_t)r1.x * 8 + c];
        acc8(acc, q0, __int_as_float(r0.y));
        acc8(acc, q1, __int_as_float(r1.y));
    }
    for (; e < end; e += 8) {
        int idx = e + g;
        int idxc = min(idx, end - 1);
        int2 r = ew[idxc];
        float w = (idx < end) ? __int_as_float(r.y) : 0.f;
        uint4 q = h[(size_t)r.x * 8 + c];
        acc8(acc, q, w);
    }

#pragma unroll
    for (int k = 0; k < 8; ++k) {
        acc[k] += __shfl_xor(acc[k], 8, 64);
        acc[k] += __shfl_xor(acc[k], 16, 64);
        acc[k] += __shfl_xor(acc[k], 32, 64);
    }

    float4 b0 = *(const float4*)&bias[c * 8];
    float4 b1 = *(const float4*)&bias[c * 8 + 4];
    float v[8];
    v[0] = acc[0] + b0.x; v[1] = acc[1] + b0.y;
    v[2] = acc[2] + b0.z; v[3] = acc[3] + b0.w;
    v[4] = acc[4] + b1.x; v[5] = acc[5] + b1.y;
    v[6] = acc[6] + b1.z; v[7] = acc[7] + b1.w;

    float m = v[0];
#pragma unroll
    for (int k = 1; k < 8; ++k) m = fmaxf(m, v[k]);
    m = fmaxf(m, __shfl_xor(m, 1, 64));
    m = fmaxf(m, __shfl_xor(m, 2, 64));
    m = fmaxf(m, __shfl_xor(m, 4, 64));
    float s = 0.f;
#pragma unroll
    for (int k = 0; k < 8; ++k) s += expf(v[k] - m);
    s += __shfl_xor(s, 1, 64);
    s += __shfl_xor(s, 2, 64);
    s += __shfl_xor(s, 4, 64);
    float ls = m + logf(s);

    if (g == 0) {
        float4 o0, o1;
        o0.x = v[0] - ls; o0.y = v[1] - ls; o0.z = v[2] - ls; o0.w = v[3] - ls;
        o1.x = v[4] - ls; o1.y = v[5] - ls; o1.z = v[6] - ls; o1.w = v[7] - ls;
        *(float4*)&out[(size_t)node * 64 + c * 8] = o0;
        *(float4*)&out[(size_t)node * 64 + c * 8 + 4] = o1;
    }
}

extern "C" void kernel_launch(void* const* d_in, const int* in_sizes, int n_in,
                              void* d_out, int out_size, void* d_ws, size_t ws_size,
                              hipStream_t stream) {
    const float* x  = (const float*)d_in[0];
    const int*   ei = (const int*)d_in[1];
    const float* W1 = (const float*)d_in[2];
    const float* b1 = (const float*)d_in[3];
    const float* W2 = (const float*)d_in[4];
    const float* b2 = (const float*)d_in[5];
    float* out = (float*)d_out;

    const int N = in_sizes[0] / 256;  // 100000
    const int E = in_sizes[1] / 2;    // 1600000
    const int NP = 102400;
    const int NB = (N + 1023) / 1024;  // scan blocks (98)
    const int NX8 = N * 32;            // N*256/8 x-cast items

    // Workspace layout (bytes; 16B-aligned segments). Total ~85 MB.
    char* ws = (char*)d_ws;
    int*   cnt     = (int*)ws;                 ws += (size_t)NP * 4;
    int*   rank    = (int*)ws;                 ws += (size_t)E * 4;
    int*   row_ptr = (int*)ws;                 ws += (size_t)(NP + 4) * 4;
    int*   bsum    = (int*)ws;                 ws += (size_t)1024 * 4;
    int*   boffs   = (int*)ws;                 ws += (size_t)1024 * 4;
    int2*  csr_ew  = (int2*)ws;                ws += (size_t)E * 8;
    unsigned short* W1t = (unsigned short*)ws; ws += (size_t)256 * 256 * 2;
    unsigned short* W2t = (unsigned short*)ws; ws += (size_t)256 * 64 * 2;
    unsigned short* xb  = (unsigned short*)ws; ws += (size_t)N * 256 * 2;
    unsigned short* h2b = (unsigned short*)ws; ws += (size_t)N * 64 * 2;

    hipMemsetAsync(cnt, 0, (size_t)N * sizeof(int), stream);

    // CSR build (one atomic pass; scatter is atomic-free)
    deg_rank_kernel<<<(E + 255) / 256, 256, 0, stream>>>(ei + E, E, cnt, rank);
    scan_part1_kernel<<<NB, 256, 0, stream>>>(cnt, bsum, N);
    scan_part2_kernel<<<1, 1024, 0, stream>>>(bsum, boffs, NB, row_ptr, N);
    scan_part3_kernel<<<NB, 256, 0, stream>>>(cnt, boffs, row_ptr, N);
    scatter_kernel<<<(E + 255) / 256, 256, 0, stream>>>(
        ei, ei + E, rank, cnt, row_ptr, csr_ew, E);

    // xb / W1t / W2t casts (one kernel)
    castxw_kernel<<<(NX8 + 65536 + 16384 + 255) / 256, 256, 0, stream>>>(
        x, W1, W2, (unsigned int*)xb, W1t, W2t, NX8);

    // h2b = bf16( relu((A xb) @ W1 + b1) @ W2 )
    megafused_kernel<<<(N + 15) / 16, 256, 0, stream>>>(
        (const uint4*)xb, csr_ew, row_ptr, cnt, b1, W1t, W2t, h2b, N);

    // out = log_softmax(A h2b + b2)
    agg64_kernel<<<(N + 3) / 4, 256, 0, stream>>>(
        (const uint4*)h2b, csr_ew, row_ptr, cnt, b2, out, N);
}